// Round 17
// baseline (486.267 us; speedup 1.0000x reference)
//
#include <hip/hip_runtime.h>
#include <hip/hip_bf16.h>

#define BB 2
#define TT 512
#define SS 400
#define HH 1024
#define VV 50257
#define MM (BB*TT)

#define NTILE 393          // ceil(VV/128)
#define NT_PAD 400         // padded: 50 panels per XCD
#define VPAD 50304         // 393*128; bf16 row padding (>= VV+3 for align pad)

typedef __attribute__((ext_vector_type(8))) short short8;
typedef __attribute__((ext_vector_type(4))) float f32x4;

#define AS1 __attribute__((address_space(1)))
#define AS3 __attribute__((address_space(3)))

// fences for the counted-vmcnt phase schedule (proven R10/R11/R16):
#define SBAR()  do { asm volatile("s_barrier" ::: "memory"); \
                     __builtin_amdgcn_sched_barrier(0); } while (0)
#define WAITV(n) do { asm volatile("s_waitcnt vmcnt(" #n ")" ::: "memory"); \
                      __builtin_amdgcn_sched_barrier(0); } while (0)
#define WAITL0() do { asm volatile("s_waitcnt lgkmcnt(0)" ::: "memory"); \
                      __builtin_amdgcn_sched_barrier(0); } while (0)

static __device__ __forceinline__ void gl_lds16(const unsigned short* g, unsigned short* l) {
    __builtin_amdgcn_global_load_lds((const AS1 unsigned int*)(g), (AS3 unsigned int*)(l), 16, 0, 0);
}

static __device__ __forceinline__ unsigned short f2bf(float f) {
    union { float f; unsigned u; } x;
    x.f = f;
    unsigned r = x.u + 0x7FFFu + ((x.u >> 16) & 1u);
    return (unsigned short)(r >> 16);
}

static __device__ __forceinline__ float bf2f(unsigned short u) {
    union { unsigned u; float f; } x;
    x.u = ((unsigned)u) << 16;
    return x.f;
}

static __device__ __forceinline__ float get_invtemp(const int* tp) {
    int iv = *tp;
    float f;
    if (iv > 0 && iv < 100000) f = (float)iv;
    else                       f = __int_as_float(iv);
    return 1.0f / f;
}

// ---- zero map ----
__global__ void zero1_k(int* a, int na) {
    int i = blockIdx.x * blockDim.x + threadIdx.x;
    int st = gridDim.x * blockDim.x;
    for (int t = i; t < na; t += st) a[t] = 0;
}

// ---- fused: convert x row -> bf16 AND p_gen = sigmoid(x.pw + pb) ----
__global__ void cvtx_pgen_k(const float* __restrict__ x, const float* __restrict__ pw,
                            const float* __restrict__ pb, unsigned short* __restrict__ xb,
                            float* __restrict__ pgen) {
    int m = blockIdx.x, tid = threadIdx.x;
    float4 v = ((const float4*)(x + (size_t)m * HH))[tid];
    ushort4 o;
    o.x = f2bf(v.x); o.y = f2bf(v.y); o.z = f2bf(v.z); o.w = f2bf(v.w);
    ((ushort4*)(xb + (size_t)m * HH))[tid] = o;
    float4 w4 = ((const float4*)pw)[tid];
    float s = v.x * w4.x + v.y * w4.y + v.z * w4.z + v.w * w4.w;
    for (int off = 32; off; off >>= 1) s += __shfl_down(s, off);
    __shared__ float red[4];
    if ((tid & 63) == 0) red[tid >> 6] = s;
    __syncthreads();
    if (tid == 0) {
        float t = red[0] + red[1] + red[2] + red[3] + pb[0];
        pgen[m] = 1.0f / (1.0f + __expf(-t));
    }
}

// ---- convert W (f32, VV rows) -> Wb (bf16, VPAD rows, zero-padded) ----
__global__ void cvt_w_k(const float* __restrict__ W, unsigned short* __restrict__ Wb) {
    size_t g = (size_t)blockIdx.x * 256 + threadIdx.x;
    size_t e0 = g * 8;
    int v = (int)(e0 >> 10);
    short8 o;
    if (v < VV) {
        float4 a = *(const float4*)(W + e0);
        float4 b = *(const float4*)(W + e0 + 4);
        o[0] = f2bf(a.x); o[1] = f2bf(a.y); o[2] = f2bf(a.z); o[3] = f2bf(a.w);
        o[4] = f2bf(b.x); o[5] = f2bf(b.y); o[6] = f2bf(b.z); o[7] = f2bf(b.w);
    } else {
        o = (short8){0,0,0,0,0,0,0,0};
    }
    *(short8*)(Wb + e0) = o;
}

// ---- canonical slot map ----
__global__ void map_build_k(const int* __restrict__ enc, int* __restrict__ mapv) {
    int t = blockIdx.x * blockDim.x + threadIdx.x;
    if (t >= BB * SS) return;
    int b = t / SS, s = t % SS;
    int id = enc[b * SS + s];
    atomicCAS(&mapv[(size_t)b * VV + id], 0, s + 1);
}

// ---- attn softmax + (1-pgen) -> slot matrix. ATOMIC-FREE (deterministic) ----
__global__ void attn_k(const float* __restrict__ attn, const int* __restrict__ enc,
                       const int* __restrict__ mapv, const float* __restrict__ pgen,
                       float* __restrict__ Aacc, const int* __restrict__ tempp) {
    int m = blockIdx.x, tid = threadIdx.x;
    int b = m >> 9;
    float invt = get_invtemp(tempp);
    __shared__ float sv[SS];
    __shared__ float ev[SS];
    __shared__ int   slt[SS];
    __shared__ float red[256];
    float loc = -1e30f;
    for (int s = tid; s < SS; s += 256) {
        float v = attn[(size_t)m * SS + s] * invt;
        sv[s] = v;
        loc = fmaxf(loc, v);
    }
    red[tid] = loc; __syncthreads();
    for (int h = 128; h; h >>= 1) { if (tid < h) red[tid] = fmaxf(red[tid], red[tid + h]); __syncthreads(); }
    float mx = red[0]; __syncthreads();
    float ls = 0.f;
    for (int s = tid; s < SS; s += 256) {
        float e = __expf(sv[s] - mx);
        ev[s] = e;
        ls += e;
        slt[s] = mapv[(size_t)b * VV + enc[b * SS + s]] - 1;
    }
    red[tid] = ls; __syncthreads();
    for (int h = 128; h; h >>= 1) { if (tid < h) red[tid] += red[tid + h]; __syncthreads(); }
    float scale = (1.0f - pgen[m]) / red[0];
    for (int s0 = tid; s0 < SS; s0 += 256) {
        float a = 0.f;
        for (int s = 0; s < SS; ++s)
            a += (slt[s] == s0) ? ev[s] : 0.f;
        Aacc[(size_t)m * SS + s0] = a * scale;
    }
}

// ---- GEMM v13: 4-buffer, 3-tiles-ahead counted-vmcnt pipeline. Same fence
//      skeleton as R10/R16 per tile (WAITV -> SBAR -> ds_read -> lgkmcnt0 ->
//      SBAR -> STAGE -> MFMA); only depth changes (WAITV(24), 4 bufs).
//      LDS 130 KB -> 1 block/CU; the 3-phase load cover replaces the lost
//      cross-block overlap. ----
template<int LOGBF>
__global__ __launch_bounds__(256) void gemm13_k(
    const unsigned short* __restrict__ xb, const unsigned short* __restrict__ Wb,
    const float* __restrict__ bias, float* __restrict__ outf,
    unsigned short* __restrict__ outb,
    float* __restrict__ pmax, float* __restrict__ psum,
    const int* __restrict__ tempp) {
    __shared__ unsigned short As0[128 * 64];   // 16 KB each; 128 KB total
    __shared__ unsigned short Bs0[128 * 64];
    __shared__ unsigned short As1[128 * 64];
    __shared__ unsigned short Bs1[128 * 64];
    __shared__ unsigned short As2[128 * 64];
    __shared__ unsigned short Bs2[128 * 64];
    __shared__ unsigned short As3[128 * 64];
    __shared__ unsigned short Bs3[128 * 64];
    __shared__ float red_mx[2][2][64];
    __shared__ float red_sm[2][2][64];

    int wgid = blockIdx.x;
    int xcd = wgid & 7;
    int l = wgid >> 3;
    int nt = xcd * 50 + (l >> 3);    // 50 panels per XCD; 8 m-tiles adjacent
    int mt = l & 7;
    if (nt >= NTILE) return;
    int m0 = mt * 128, n0 = nt * 128;

    int tid = threadIdx.x;
    int lane = tid & 63, w = tid >> 6;
    int wr = w >> 1, wc = w & 1;
    int r15 = lane & 15, kg = lane >> 4;

    // staging source offsets (global pre-swizzled so linear LDS holds XOR layout)
    size_t aoff[4], boff[4];
    int ldst[4];
#pragma unroll
    for (int i = 0; i < 4; i++) {
        int q = i * 256 + tid;
        int row = q >> 3;
        int jc = (q & 7) ^ (row & 7);
        aoff[i] = (size_t)(m0 + row) * HH + jc * 8;
        boff[i] = (size_t)(n0 + row) * HH + jc * 8;
        ldst[i] = (i * 256 + w * 64) * 8;
    }

    f32x4 acc[4][4];
#pragma unroll
    for (int i = 0; i < 4; i++)
#pragma unroll
        for (int j = 0; j < 4; j++) acc[i][j] = (f32x4){0.f, 0.f, 0.f, 0.f};

    // 8 gl_lds per STAGE (vmcnt += 8)
#define STAGE(A_, B_, k0_) do { \
    _Pragma("unroll") for (int i_ = 0; i_ < 4; i_++) { \
        gl_lds16(xb + aoff[i_] + (k0_), (A_) + ldst[i_]); \
        gl_lds16(Wb + boff[i_] + (k0_), (B_) + ldst[i_]); \
    } } while (0)
    // 16 ds_read_b128 per tile (A 8 + B 8), XOR-swizzled addresses
#define LOADFRAG(AF_, BF_, A_, B_) do { \
    _Pragma("unroll") for (int h_ = 0; h_ < 2; h_++) { \
        _Pragma("unroll") for (int mi_ = 0; mi_ < 4; mi_++) { \
            int row_ = wr * 64 + mi_ * 16 + r15; \
            int jc_ = ((h_ << 2) | kg) ^ (row_ & 7); \
            AF_[h_ * 4 + mi_] = *(const short8*)&(A_)[row_ * 64 + jc_ * 8]; \
        } \
        _Pragma("unroll") for (int ni_ = 0; ni_ < 4; ni_++) { \
            int row_ = wc * 64 + ni_ * 16 + r15; \
            int jc_ = ((h_ << 2) | kg) ^ (row_ & 7); \
            BF_[h_ * 4 + ni_] = *(const short8*)&(B_)[row_ * 64 + jc_ * 8]; \
        } \
    } } while (0)
#define MFMA32(AF_, BF_) do { \
    __builtin_amdgcn_s_setprio(1); \
    _Pragma("unroll") for (int h_ = 0; h_ < 2; h_++) \
    _Pragma("unroll") for (int mi_ = 0; mi_ < 4; mi_++) \
    _Pragma("unroll") for (int ni_ = 0; ni_ < 4; ni_++) \
        acc[mi_][ni_] = __builtin_amdgcn_mfma_f32_16x16x32_bf16( \
            AF_[h_ * 4 + mi_], BF_[h_ * 4 + ni_], acc[mi_][ni_], 0, 0, 0); \
    __builtin_amdgcn_s_setprio(0); \
    } while (0)

    // prologue: tiles 0-3 in flight (32 outstanding loads/wave)
    STAGE(As0, Bs0, 0);
    STAGE(As1, Bs1, 64);
    STAGE(As2, Bs2, 128);
    STAGE(As3, Bs3, 192);

    short8 af[8], bf[8];
    // steady state: tiles 0..11, staging tiles 4..15 three phases ahead.
    // invariant at each WAITV(24): 32 outstanding; retires oldest tile's 8.
    for (int q = 0; q < 3; ++q) {
        int kb = q * 256;
        WAITV(24); SBAR();
        LOADFRAG(af, bf, As0, Bs0);
        WAITL0(); SBAR();
        STAGE(As0, Bs0, kb + 256);
        MFMA32(af, bf);

        WAITV(24); SBAR();
        LOADFRAG(af, bf, As1, Bs1);
        WAITL0(); SBAR();
        STAGE(As1, Bs1, kb + 320);
        MFMA32(af, bf);

        WAITV(24); SBAR();
        LOADFRAG(af, bf, As2, Bs2);
        WAITL0(); SBAR();
        STAGE(As2, Bs2, kb + 384);
        MFMA32(af, bf);

        WAITV(24); SBAR();
        LOADFRAG(af, bf, As3, Bs3);
        WAITL0(); SBAR();
        STAGE(As3, Bs3, kb + 448);
        MFMA32(af, bf);
    }
    // tail: tiles 12..15, draining 24 -> 16 -> 8 -> 0
    WAITV(24); SBAR();
    LOADFRAG(af, bf, As0, Bs0);
    MFMA32(af, bf);
    WAITV(16); SBAR();
    LOADFRAG(af, bf, As1, Bs1);
    MFMA32(af, bf);
    WAITV(8); SBAR();
    LOADFRAG(af, bf, As2, Bs2);
    MFMA32(af, bf);
    WAITV(0); SBAR();
    LOADFRAG(af, bf, As3, Bs3);
    MFMA32(af, bf);
#undef STAGE
#undef LOADFRAG
#undef MFMA32

    // ---- epilogue: bias add, fused per-row (max, sumexp) partials, logit store ----
    float invt = get_invtemp(tempp);
    float bv[4]; bool vld[4]; int gn[4];
#pragma unroll
    for (int ni = 0; ni < 4; ni++) {
        gn[ni] = n0 + wc * 64 + ni * 16 + r15;
        vld[ni] = gn[ni] < VV;
        bv[ni] = vld[ni] ? bias[gn[ni]] : 0.f;
    }
#pragma unroll
    for (int mi = 0; mi < 4; mi++) {
#pragma unroll
        for (int j = 0; j < 4; j++) {
            float mx = -1e30f;
#pragma unroll
            for (int ni = 0; ni < 4; ni++)
                if (vld[ni]) mx = fmaxf(mx, (acc[mi][ni][j] + bv[ni]) * invt);
            float sm = 0.f;
#pragma unroll
            for (int ni = 0; ni < 4; ni++)
                if (vld[ni]) sm += __expf((acc[mi][ni][j] + bv[ni]) * invt - mx);
#pragma unroll
            for (int o = 1; o < 16; o <<= 1) {
                float m2 = __shfl_xor(mx, o);
                float s2 = __shfl_xor(sm, o);
                float nm = fmaxf(mx, m2);
                sm = sm * __expf(mx - nm) + s2 * __expf(m2 - nm);
                mx = nm;
            }
            if (r15 == 0) {
                red_mx[wr][wc][mi * 16 + kg * 4 + j] = mx;
                red_sm[wr][wc][mi * 16 + kg * 4 + j] = sm;
            }
        }
    }
#pragma unroll
    for (int ni = 0; ni < 4; ni++) {
        if (vld[ni]) {
#pragma unroll
            for (int mi = 0; mi < 4; mi++) {
                int gmb = m0 + wr * 64 + mi * 16 + (kg << 2);
#pragma unroll
                for (int j = 0; j < 4; j++) {
                    int row = gmb + j;
                    if (LOGBF)  // per-row pad (row&3) => finalize reads 8B-aligned
                        outb[(size_t)row * VPAD + (row & 3) + gn[ni]] = f2bf(acc[mi][ni][j] + bv[ni]);
                    else
                        outf[(size_t)row * VV + gn[ni]] = acc[mi][ni][j] + bv[ni];
                }
            }
        }
    }
    __syncthreads();
    if (tid < 128) {
        int r = tid & 63, wr2 = tid >> 6;
        float m1 = red_mx[wr2][0][r], s1 = red_sm[wr2][0][r];
        float m2 = red_mx[wr2][1][r], s2 = red_sm[wr2][1][r];
        float nm = fmaxf(m1, m2);
        float s = s1 * __expf(m1 - nm) + s2 * __expf(m2 - nm);
        int gm = m0 + wr2 * 64 + r;
        pmax[(size_t)gm * NT_PAD + nt] = nm;
        psum[(size_t)gm * NT_PAD + nt] = s;
    }
}

// ---- combine per-tile partials -> lse[m], one wave per row ----
__global__ void lse_wave_k(const float* __restrict__ pmax, const float* __restrict__ psum,
                           float* __restrict__ lse) {
    int gw = (blockIdx.x * blockDim.x + threadIdx.x) >> 6;
    int ln = threadIdx.x & 63;
    if (gw >= MM) return;
    const float* pm = pmax + (size_t)gw * NT_PAD;
    const float* ps = psum + (size_t)gw * NT_PAD;
    float M = -1e30f, S = 0.f;
    for (int t = ln; t < NTILE; t += 64) {
        float m2 = pm[t], s2 = ps[t];
        float nm = fmaxf(M, m2);
        S = S * __expf(M - nm) + s2 * __expf(m2 - nm);
        M = nm;
    }
#pragma unroll
    for (int o = 1; o < 64; o <<= 1) {
        float m2 = __shfl_xor(M, o);
        float s2 = __shfl_xor(S, o);
        float nm = fmaxf(M, m2);
        S = S * __expf(M - nm) + s2 * __expf(m2 - nm);
        M = nm;
    }
    if (ln == 0) lse[gw] = M + __logf(S);
}

// ---- finalize DENSE: no map read — out = log(pg*exp(l-L)+1e-40).
//      Mapped entries corrected afterwards by scatter_fix_k. ----
__global__ void finalize_dense_k(const unsigned short* __restrict__ logb,
                                 float* __restrict__ out, const float* __restrict__ pgen,
                                 const float* __restrict__ lse, const int* __restrict__ tempp) {
    int m = blockIdx.y;
    float invt = get_invtemp(tempp);
    float pg = pgen[m], L = lse[m];
    int sk = (-m) & 3, pad = m & 3;
    int nchunk = (VV - sk) >> 2;
    const unsigned short* lrow = logb + (size_t)m * VPAD + pad;
    size_t base = (size_t)m * VV;
    int c = blockIdx.x * 256 + threadIdx.x;
    if (c < nchunk) {
        int v0 = sk + 4 * c;
        ushort4 lb = *(const ushort4*)(lrow + v0);   // (pad+sk)%4==0 -> aligned
        unsigned short ls[4] = {lb.x, lb.y, lb.z, lb.w};
        float rs[4];
#pragma unroll
        for (int j = 0; j < 4; j++)
            rs[j] = __logf(pg * __expf(bf2f(ls[j]) * invt - L) + 1e-40f);
        float4 o4 = {rs[0], rs[1], rs[2], rs[3]};
        *(float4*)(out + base + sk + 4 * c) = o4;    // aligned 16B
    }
    if (blockIdx.x == 0 && threadIdx.x == 0) {
        for (int v = 0; v < sk; v++)
            out[base + v] = __logf(pg * __expf(bf2f(lrow[v]) * invt - L) + 1e-40f);
        for (int v = sk + 4 * nchunk; v < VV; v++)
            out[base + v] = __logf(pg * __expf(bf2f(lrow[v]) * invt - L) + 1e-40f);
    }
}

// ---- sparse correction: one block per (b,s) slot; rewrites mapped entries.
//      Each (m, canonical id) written exactly once -> deterministic. ----
__global__ void scatter_fix_k(const int* __restrict__ enc, const int* __restrict__ mapv,
                              const unsigned short* __restrict__ logb,
                              float* __restrict__ out, const float* __restrict__ pgen,
                              const float* __restrict__ lse, const float* __restrict__ Aacc,
                              const int* __restrict__ tempp) {
    int t = blockIdx.x;            // 0 .. BB*SS-1
    int b = t / SS, s = t % SS;
    int id = enc[b * SS + s];
    if (mapv[(size_t)b * VV + id] - 1 != s) return;   // not the canonical slot
    float invt = get_invtemp(tempp);
    int tid = threadIdx.x;
    for (int mo = tid; mo < TT; mo += 256) {
        int m = b * TT + mo;
        float l = bf2f(logb[(size_t)m * VPAD + (m & 3) + id]);
        float p = pgen[m] * __expf(l * invt - lse[m]) + Aacc[(size_t)m * SS + s];
        out[(size_t)m * VV + id] = __logf(p + 1e-40f);
    }
}

// ---- finalize in-place from f32 logits (middle/fallback path) ----
__global__ void finalize_k(float* __restrict__ out, const float* __restrict__ pgen,
                           const float* __restrict__ lse, const int* __restrict__ mapv,
                           const float* __restrict__ Aacc, const int* __restrict__ tempp) {
    int m = blockIdx.y;
    int b = m >> 9;
    float invt = get_invtemp(tempp);
    float pg = pgen[m], L = lse[m];
    size_t base = (size_t)m * VV;
    const int* mrow = mapv + (size_t)b * VV;
    const float* arow = Aacc + (size_t)m * SS;
    int sk = (-m) & 3;
    int nchunk = (VV - sk) >> 2;
    int c = blockIdx.x * 256 + threadIdx.x;
    if (c < nchunk) {
        int v0 = sk + 4 * c;
        float4 l4 = *(const float4*)(out + base + v0);
        float xs[4] = {l4.x, l4.y, l4.z, l4.w};
        float rs[4];
#pragma unroll
        for (int j = 0; j < 4; j++) {
            float p = pg * __expf(xs[j] * invt - L);
            int jm = mrow[v0 + j];
            if (jm) p += arow[jm - 1];
            rs[j] = __logf(p + 1e-40f);
        }
        float4 o4 = {rs[0], rs[1], rs[2], rs[3]};
        *(float4*)(out + base + v0) = o4;
    }
    if (blockIdx.x == 0 && threadIdx.x == 0) {
        for (int v = 0; v < sk; v++) {
            float p = pg * __expf(out[base + v] * invt - L);
            int jm = mrow[v];
            if (jm) p += arow[jm - 1];
            out[base + v] = __logf(p + 1e-40f);
        }
        for (int v = sk + 4 * nchunk; v < VV; v++) {
            float p = pg * __expf(out[base + v] * invt - L);
            int jm = mrow[v];
            if (jm) p += arow[jm - 1];
            out[base + v] = __logf(p + 1e-40f);
        }
    }
}

// ---- fallback GEMM (round-1 version, f32 W inline convert) ----
__global__ __launch_bounds__(256) void gemm_old_k(
    const unsigned short* __restrict__ xb, const float* __restrict__ W,
    const float* __restrict__ bias, float* __restrict__ out) {
    __shared__ unsigned short As[128][40];
    __shared__ unsigned short Bs[128][40];
    int bid = blockIdx.x;
    int mt = bid & 7;
    int nt = bid >> 3;
    int m0 = mt * 128, n0 = nt * 128;
    int tid = threadIdx.x;
    int lid = tid & 63, w = tid >> 6;
    int wr = w >> 1, wc = w & 1;
    int row16 = lid & 15, kg = lid >> 4;

    f32x4 acc[4][4];
#pragma unroll
    for (int i = 0; i < 4; i++)
#pragma unroll
        for (int j = 0; j < 4; j++) acc[i][j] = (f32x4){0.f, 0.f, 0.f, 0.f};

    int tr = tid >> 3;
    int tc = (tid & 7) << 2;

    for (int kt = 0; kt < HH / 32; ++kt) {
        int k0 = kt * 32;
        __syncthreads();
#pragma unroll
        for (int i = 0; i < 4; i++) {
            int r = tr + 32 * i;
            ushort4 a4 = *(const ushort4*)&xb[(size_t)(m0 + r) * HH + k0 + tc];
            *(ushort4*)&As[r][tc] = a4;
            int v = n0 + r; v = (v < VV) ? v : (VV - 1);
            float4 w4 = *(const float4*)&W[(size_t)v * HH + k0 + tc];
            ushort4 b4;
            b4.x = f2bf(w4.x); b4.y = f2bf(w4.y); b4.z = f2bf(w4.z); b4.w = f2bf(w4.w);
            *(ushort4*)&Bs[r][tc] = b4;
        }
        __syncthreads();
        short8 af[4], bf[4];
#pragma unroll
        for (int i = 0; i < 4; i++) {
            af[i] = *(const short8*)&As[wr * 64 + i * 16 + row16][kg * 8];
            bf[i] = *(const short8*)&Bs[wc * 64 + i * 16 + row16][kg * 8];
        }
#pragma unroll
        for (int mi = 0; mi < 4; mi++)
#pragma unroll
            for (int ni = 0; ni < 4; ni++)
                acc[mi][ni] = __builtin_amdgcn_mfma_f32_16x16x32_bf16(af[mi], bf[ni], acc[mi][ni], 0, 0, 0);
    }
#pragma unroll
    for (int ni = 0; ni < 4; ni++) {
        int gnv = n0 + wc * 64 + ni * 16 + row16;
        if (gnv < VV) {
            float bvv = bias[gnv];
#pragma unroll
            for (int mi = 0; mi < 4; mi++) {
                int gmb = m0 + wr * 64 + mi * 16 + (kg << 2);
#pragma unroll
                for (int j = 0; j < 4; j++)
                    out[(size_t)(gmb + j) * VV + gnv] = acc[mi][ni][j] + bvv;
            }
        }
    }
}

// ---- per-row lse over V (fallback path only) ----
__global__ void rowreduce_k(const float* __restrict__ out, float* __restrict__ lse,
                            const int* __restrict__ tempp) {
    int m = blockIdx.x, tid = threadIdx.x;
    float invt = get_invtemp(tempp);
    const float* row = out + (size_t)m * VV;
    int sk = (-m) & 3;
    int nchunk = (VV - sk) >> 2;
    float mi = -1e30f, si = 0.f;
    for (int c = tid; c < nchunk; c += 256) {
        float4 x4 = *(const float4*)(row + sk + 4 * c);
        float xs[4] = {x4.x, x4.y, x4.z, x4.w};
#pragma unroll
        for (int j = 0; j < 4; j++) {
            float x = xs[j] * invt;
            float nm = fmaxf(mi, x);
            si = si * __expf(mi - nm) + __expf(x - nm);
            mi = nm;
        }
    }
    if (tid == 0) {
        for (int v = 0; v < sk; v++) {
            float x = row[v] * invt;
            float nm = fmaxf(mi, x);
            si = si * __expf(mi - nm) + __expf(x - nm);
            mi = nm;
        }
        for (int v = sk + 4 * nchunk; v < VV; v++) {
            float x = row[v] * invt;
            float nm = fmaxf(mi, x);
            si = si * __expf(mi - nm) + __expf(x - nm);
            mi = nm;
        }
    }
    __shared__ float sm[256], ss[256];
    sm[tid] = mi; ss[tid] = si; __syncthreads();
    for (int h = 128; h; h >>= 1) {
        if (tid < h) {
            float m2 = sm[tid + h], s2 = ss[tid + h];
            float nm = fmaxf(sm[tid], m2);
            ss[tid] = ss[tid] * __expf(sm[tid] - nm) + s2 * __expf(m2 - nm);
            sm[tid] = nm;
        }
        __syncthreads();
    }
    if (tid == 0) lse[m] = sm[0] + __logf(ss[0]);
}

extern "C" void kernel_launch(void* const* d_in, const int* in_sizes, int n_in,
                              void* d_out, int out_size, void* d_ws, size_t ws_size,
                              hipStream_t stream) {
    const float* x      = (const float*)d_in[0];
    const float* attn   = (const float*)d_in[1];
    const int*   enc    = (const int*)d_in[2];
    const int*   temp   = (const int*)d_in[3];
    const float* proj_w = (const float*)d_in[4];
    const float* proj_b = (const float*)d_in[5];
    const float* pgen_w = (const float*)d_in[6];
    const float* pgen_b = (const float*)d_in[7];
    float* out = (float*)d_out;

    char* ws = (char*)d_ws;
    const size_t WB_BYTES = (size_t)VPAD * HH * 2;       // 103,022,592

    size_t o_wb   = 0;
    size_t o_xb   = o_wb + WB_BYTES;
    size_t o_pgen = o_xb + 2097152;
    size_t o_lse  = o_pgen + 4096;
    size_t o_map  = o_lse + 4096;
    size_t o_aacc = o_map + 402432;
    size_t o_pmax = o_aacc + (size_t)MM * SS * 4;
    size_t o_psum = o_pmax + (size_t)MM * NT_PAD * 4;
    size_t o_logb = o_psum + (size_t)MM * NT_PAD * 4;    // 110,445,568
    size_t need_mid = o_logb;                            // ~110.4 MB
    size_t need_big = o_logb + (size_t)MM * VPAD * 2;    // ~213.5 MB

    if (ws_size >= need_mid) {
        unsigned short* wb   = (unsigned short*)(ws + o_wb);
        unsigned short* xb   = (unsigned short*)(ws + o_xb);
        float*          pgen = (float*)(ws + o_pgen);
        float*          lse  = (float*)(ws + o_lse);
        int*            mapv = (int*)(ws + o_map);
        float*          Aacc = (float*)(ws + o_aacc);
        float*          pmax = (float*)(ws + o_pmax);
        float*          psum = (float*)(ws + o_psum);
        unsigned short* logb = (unsigned short*)(ws + o_logb);

        zero1_k<<<256, 256, 0, stream>>>(mapv, BB * VV);
        cvtx_pgen_k<<<MM, 256, 0, stream>>>(x, pgen_w, pgen_b, xb, pgen);
        cvt_w_k<<<(VPAD * HH / 8 + 255) / 256, 256, 0, stream>>>(proj_w, wb);
        map_build_k<<<4, 256, 0, stream>>>(enc, mapv);
        attn_k<<<MM, 256, 0, stream>>>(attn, enc, mapv, pgen, Aacc, temp);
        if (ws_size >= need_big) {
            gemm13_k<1><<<8 * NT_PAD, 256, 0, stream>>>(xb, wb, proj_b, out, logb, pmax, psum, temp);
            lse_wave_k<<<256, 256, 0, stream>>>(pmax, psum, lse);
            finalize_dense_k<<<dim3(50, MM), 256, 0, stream>>>(logb, out, pgen, lse, temp);
            scatter_fix_k<<<BB * SS, 256, 0, stream>>>(enc, mapv, logb, out, pgen, lse, Aacc, temp);
        } else {
            gemm13_k<0><<<8 * NT_PAD, 256, 0, stream>>>(xb, wb, proj_b, out, logb, pmax, psum, temp);
            lse_wave_k<<<256, 256, 0, stream>>>(pmax, psum, lse);
            finalize_k<<<dim3(50, MM), 256, 0, stream>>>(out, pgen, lse, mapv, Aacc, temp);
        }
    } else {
        unsigned short* xb   = (unsigned short*)(ws + 0);
        float*          pgen = (float*)(ws + 2097152);
        float*          lse  = (float*)(ws + 2101248);
        int*            mapv = (int*)(ws + 2105344);
        float*          Aacc = (float*)(ws + 2507776);

        zero1_k<<<256, 256, 0, stream>>>(mapv, BB * VV);
        cvtx_pgen_k<<<MM, 256, 0, stream>>>(x, pgen_w, pgen_b, xb, pgen);
        map_build_k<<<4, 256, 0, stream>>>(enc, mapv);
        attn_k<<<MM, 256, 0, stream>>>(attn, enc, mapv, pgen, Aacc, temp);
        gemm_old_k<<<8 * NTILE, 256, 0, stream>>>(xb, proj_w, proj_b, out);
        rowreduce_k<<<MM, 256, 0, stream>>>(out, lse, temp);
        finalize_k<<<dim3(50, MM), 256, 0, stream>>>(out, pgen, lse, mapv, Aacc, temp);
    }
}

// Round 18
// 404.162 us; speedup vs baseline: 1.2032x; 1.2032x over previous
//
#include <hip/hip_runtime.h>
#include <hip/hip_bf16.h>

#define BB 2
#define TT 512
#define SS 400
#define HH 1024
#define VV 50257
#define MM (BB*TT)

#define NTILE 393          // ceil(VV/128)
#define NT_PAD 400         // padded: 50 panels per XCD
#define VPAD 50304         // 393*128; bf16 row padding (>= VV+3 for align pad)

typedef __attribute__((ext_vector_type(8))) short short8;
typedef __attribute__((ext_vector_type(4))) float f32x4;

#define AS1 __attribute__((address_space(1)))
#define AS3 __attribute__((address_space(3)))

// fences for the counted-vmcnt phase schedule (proven R10/R11/R16):
#define SBAR()  do { asm volatile("s_barrier" ::: "memory"); \
                     __builtin_amdgcn_sched_barrier(0); } while (0)
#define WAITV(n) do { asm volatile("s_waitcnt vmcnt(" #n ")" ::: "memory"); \
                      __builtin_amdgcn_sched_barrier(0); } while (0)
#define WAITL0() do { asm volatile("s_waitcnt lgkmcnt(0)" ::: "memory"); \
                      __builtin_amdgcn_sched_barrier(0); } while (0)

static __device__ __forceinline__ void gl_lds16(const unsigned short* g, unsigned short* l) {
    __builtin_amdgcn_global_load_lds((const AS1 unsigned int*)(g), (AS3 unsigned int*)(l), 16, 0, 0);
}

static __device__ __forceinline__ unsigned short f2bf(float f) {
    union { float f; unsigned u; } x;
    x.f = f;
    unsigned r = x.u + 0x7FFFu + ((x.u >> 16) & 1u);
    return (unsigned short)(r >> 16);
}

static __device__ __forceinline__ float bf2f(unsigned short u) {
    union { unsigned u; float f; } x;
    x.u = ((unsigned)u) << 16;
    return x.f;
}

static __device__ __forceinline__ float get_invtemp(const int* tp) {
    int iv = *tp;
    float f;
    if (iv > 0 && iv < 100000) f = (float)iv;
    else                       f = __int_as_float(iv);
    return 1.0f / f;
}

// ---- zero map ----
__global__ void zero1_k(int* a, int na) {
    int i = blockIdx.x * blockDim.x + threadIdx.x;
    int st = gridDim.x * blockDim.x;
    for (int t = i; t < na; t += st) a[t] = 0;
}

// ---- fused: convert x row -> bf16 AND p_gen = sigmoid(x.pw + pb) ----
__global__ void cvtx_pgen_k(const float* __restrict__ x, const float* __restrict__ pw,
                            const float* __restrict__ pb, unsigned short* __restrict__ xb,
                            float* __restrict__ pgen) {
    int m = blockIdx.x, tid = threadIdx.x;
    float4 v = ((const float4*)(x + (size_t)m * HH))[tid];
    ushort4 o;
    o.x = f2bf(v.x); o.y = f2bf(v.y); o.z = f2bf(v.z); o.w = f2bf(v.w);
    ((ushort4*)(xb + (size_t)m * HH))[tid] = o;
    float4 w4 = ((const float4*)pw)[tid];
    float s = v.x * w4.x + v.y * w4.y + v.z * w4.z + v.w * w4.w;
    for (int off = 32; off; off >>= 1) s += __shfl_down(s, off);
    __shared__ float red[4];
    if ((tid & 63) == 0) red[tid >> 6] = s;
    __syncthreads();
    if (tid == 0) {
        float t = red[0] + red[1] + red[2] + red[3] + pb[0];
        pgen[m] = 1.0f / (1.0f + __expf(-t));
    }
}

// ---- convert W (f32, VV rows) -> Wb (bf16, VPAD rows, zero-padded) ----
__global__ void cvt_w_k(const float* __restrict__ W, unsigned short* __restrict__ Wb) {
    size_t g = (size_t)blockIdx.x * 256 + threadIdx.x;
    size_t e0 = g * 8;
    int v = (int)(e0 >> 10);
    short8 o;
    if (v < VV) {
        float4 a = *(const float4*)(W + e0);
        float4 b = *(const float4*)(W + e0 + 4);
        o[0] = f2bf(a.x); o[1] = f2bf(a.y); o[2] = f2bf(a.z); o[3] = f2bf(a.w);
        o[4] = f2bf(b.x); o[5] = f2bf(b.y); o[6] = f2bf(b.z); o[7] = f2bf(b.w);
    } else {
        o = (short8){0,0,0,0,0,0,0,0};
    }
    *(short8*)(Wb + e0) = o;
}

// ---- canonical slot map ----
__global__ void map_build_k(const int* __restrict__ enc, int* __restrict__ mapv) {
    int t = blockIdx.x * blockDim.x + threadIdx.x;
    if (t >= BB * SS) return;
    int b = t / SS, s = t % SS;
    int id = enc[b * SS + s];
    atomicCAS(&mapv[(size_t)b * VV + id], 0, s + 1);
}

// ---- attn softmax + (1-pgen) -> slot matrix. ATOMIC-FREE (deterministic) ----
__global__ void attn_k(const float* __restrict__ attn, const int* __restrict__ enc,
                       const int* __restrict__ mapv, const float* __restrict__ pgen,
                       float* __restrict__ Aacc, const int* __restrict__ tempp) {
    int m = blockIdx.x, tid = threadIdx.x;
    int b = m >> 9;
    float invt = get_invtemp(tempp);
    __shared__ float sv[SS];
    __shared__ float ev[SS];
    __shared__ int   slt[SS];
    __shared__ float red[256];
    float loc = -1e30f;
    for (int s = tid; s < SS; s += 256) {
        float v = attn[(size_t)m * SS + s] * invt;
        sv[s] = v;
        loc = fmaxf(loc, v);
    }
    red[tid] = loc; __syncthreads();
    for (int h = 128; h; h >>= 1) { if (tid < h) red[tid] = fmaxf(red[tid], red[tid + h]); __syncthreads(); }
    float mx = red[0]; __syncthreads();
    float ls = 0.f;
    for (int s = tid; s < SS; s += 256) {
        float e = __expf(sv[s] - mx);
        ev[s] = e;
        ls += e;
        slt[s] = mapv[(size_t)b * VV + enc[b * SS + s]] - 1;
    }
    red[tid] = ls; __syncthreads();
    for (int h = 128; h; h >>= 1) { if (tid < h) red[tid] += red[tid + h]; __syncthreads(); }
    float scale = (1.0f - pgen[m]) / red[0];
    for (int s0 = tid; s0 < SS; s0 += 256) {
        float a = 0.f;
        for (int s = 0; s < SS; ++s)
            a += (slt[s] == s0) ? ev[s] : 0.f;
        Aacc[(size_t)m * SS + s0] = a * scale;
    }
}

// ---- GEMM v10b (R11/R16 verbatim — best measured: ~207 µs) ----
template<int LOGBF>
__global__ __launch_bounds__(256) void gemm10_k(
    const unsigned short* __restrict__ xb, const unsigned short* __restrict__ Wb,
    const float* __restrict__ bias, float* __restrict__ outf,
    unsigned short* __restrict__ outb,
    float* __restrict__ pmax, float* __restrict__ psum,
    const int* __restrict__ tempp) {
    __shared__ unsigned short As0[128 * 64];   // 16 KB each; 64 KB total
    __shared__ unsigned short Bs0[128 * 64];
    __shared__ unsigned short As1[128 * 64];
    __shared__ unsigned short Bs1[128 * 64];
    __shared__ float red_mx[2][2][64];
    __shared__ float red_sm[2][2][64];

    int wgid = blockIdx.x;
    int xcd = wgid & 7;
    int l = wgid >> 3;
    int nt = xcd * 50 + (l >> 3);    // 50 panels per XCD; 8 m-tiles adjacent
    int mt = l & 7;
    if (nt >= NTILE) return;
    int m0 = mt * 128, n0 = nt * 128;

    int tid = threadIdx.x;
    int lane = tid & 63, w = tid >> 6;
    int wr = w >> 1, wc = w & 1;
    int r15 = lane & 15, kg = lane >> 4;

    // staging source offsets (global pre-swizzled so linear LDS holds XOR layout)
    size_t aoff[4], boff[4];
    int ldst[4];
#pragma unroll
    for (int i = 0; i < 4; i++) {
        int q = i * 256 + tid;
        int row = q >> 3;
        int jc = (q & 7) ^ (row & 7);
        aoff[i] = (size_t)(m0 + row) * HH + jc * 8;
        boff[i] = (size_t)(n0 + row) * HH + jc * 8;
        ldst[i] = (i * 256 + w * 64) * 8;
    }

    f32x4 acc[4][4];
#pragma unroll
    for (int i = 0; i < 4; i++)
#pragma unroll
        for (int j = 0; j < 4; j++) acc[i][j] = (f32x4){0.f, 0.f, 0.f, 0.f};

    // 8 gl_lds per STAGE (vmcnt += 8)
#define STAGE(A_, B_, k0_) do { \
    _Pragma("unroll") for (int i_ = 0; i_ < 4; i_++) { \
        gl_lds16(xb + aoff[i_] + (k0_), (A_) + ldst[i_]); \
        gl_lds16(Wb + boff[i_] + (k0_), (B_) + ldst[i_]); \
    } } while (0)
    // 16 ds_read_b128 per tile (A 8 + B 8), XOR-swizzled addresses
#define LOADFRAG(AF_, BF_, A_, B_) do { \
    _Pragma("unroll") for (int h_ = 0; h_ < 2; h_++) { \
        _Pragma("unroll") for (int mi_ = 0; mi_ < 4; mi_++) { \
            int row_ = wr * 64 + mi_ * 16 + r15; \
            int jc_ = ((h_ << 2) | kg) ^ (row_ & 7); \
            AF_[h_ * 4 + mi_] = *(const short8*)&(A_)[row_ * 64 + jc_ * 8]; \
        } \
        _Pragma("unroll") for (int ni_ = 0; ni_ < 4; ni_++) { \
            int row_ = wc * 64 + ni_ * 16 + r15; \
            int jc_ = ((h_ << 2) | kg) ^ (row_ & 7); \
            BF_[h_ * 4 + ni_] = *(const short8*)&(B_)[row_ * 64 + jc_ * 8]; \
        } \
    } } while (0)
#define MFMA32(AF_, BF_) do { \
    __builtin_amdgcn_s_setprio(1); \
    _Pragma("unroll") for (int h_ = 0; h_ < 2; h_++) \
    _Pragma("unroll") for (int mi_ = 0; mi_ < 4; mi_++) \
    _Pragma("unroll") for (int ni_ = 0; ni_ < 4; ni_++) \
        acc[mi_][ni_] = __builtin_amdgcn_mfma_f32_16x16x32_bf16( \
            AF_[h_ * 4 + mi_], BF_[h_ * 4 + ni_], acc[mi_][ni_], 0, 0, 0); \
    __builtin_amdgcn_s_setprio(0); \
    } while (0)

    // prologue: tiles 0,1 in flight (16 outstanding loads/wave)
    STAGE(As0, Bs0, 0);
    STAGE(As1, Bs1, 64);

    short8 af[8], bf[8];
    // steady state: tiles 0..13 (stage tiles 2..15)
    for (int p = 0; p < 7; ++p) {
        int k4 = p * 128;
        // tile 2p (buf0)
        WAITV(8);                    // my 8 buf0 loads retired
        SBAR();                      // => ALL waves' buf0 DMA landed
        LOADFRAG(af, bf, As0, Bs0);
        WAITL0();                    // my ds_reads of buf0 complete
        SBAR();                      // => ALL waves done reading buf0
        STAGE(As0, Bs0, k4 + 128);   // re-stage buf0 with tile 2p+2; flies
        MFMA32(af, bf);              // overlap staging latency
        // tile 2p+1 (buf1)
        WAITV(8);
        SBAR();
        LOADFRAG(af, bf, As1, Bs1);
        WAITL0();
        SBAR();
        STAGE(As1, Bs1, k4 + 192);
        MFMA32(af, bf);
    }
    // tile 14 (buf0): no more staging
    WAITV(8);
    SBAR();
    LOADFRAG(af, bf, As0, Bs0);
    MFMA32(af, bf);
    // tile 15 (buf1)
    WAITV(0);
    SBAR();
    LOADFRAG(af, bf, As1, Bs1);
    MFMA32(af, bf);
#undef STAGE
#undef LOADFRAG
#undef MFMA32

    // ---- epilogue: bias add, fused per-row (max, sumexp) partials, logit store ----
    float invt = get_invtemp(tempp);
    float bv[4]; bool vld[4]; int gn[4];
#pragma unroll
    for (int ni = 0; ni < 4; ni++) {
        gn[ni] = n0 + wc * 64 + ni * 16 + r15;
        vld[ni] = gn[ni] < VV;
        bv[ni] = vld[ni] ? bias[gn[ni]] : 0.f;
    }
#pragma unroll
    for (int mi = 0; mi < 4; mi++) {
#pragma unroll
        for (int j = 0; j < 4; j++) {
            float mx = -1e30f;
#pragma unroll
            for (int ni = 0; ni < 4; ni++)
                if (vld[ni]) mx = fmaxf(mx, (acc[mi][ni][j] + bv[ni]) * invt);
            float sm = 0.f;
#pragma unroll
            for (int ni = 0; ni < 4; ni++)
                if (vld[ni]) sm += __expf((acc[mi][ni][j] + bv[ni]) * invt - mx);
#pragma unroll
            for (int o = 1; o < 16; o <<= 1) {
                float m2 = __shfl_xor(mx, o);
                float s2 = __shfl_xor(sm, o);
                float nm = fmaxf(mx, m2);
                sm = sm * __expf(mx - nm) + s2 * __expf(m2 - nm);
                mx = nm;
            }
            if (r15 == 0) {
                red_mx[wr][wc][mi * 16 + kg * 4 + j] = mx;
                red_sm[wr][wc][mi * 16 + kg * 4 + j] = sm;
            }
        }
    }
#pragma unroll
    for (int ni = 0; ni < 4; ni++) {
        if (vld[ni]) {
#pragma unroll
            for (int mi = 0; mi < 4; mi++) {
                int gmb = m0 + wr * 64 + mi * 16 + (kg << 2);
#pragma unroll
                for (int j = 0; j < 4; j++) {
                    int row = gmb + j;
                    if (LOGBF)  // per-row pad (row&3) => finalize reads 8B-aligned
                        outb[(size_t)row * VPAD + (row & 3) + gn[ni]] = f2bf(acc[mi][ni][j] + bv[ni]);
                    else
                        outf[(size_t)row * VV + gn[ni]] = acc[mi][ni][j] + bv[ni];
                }
            }
        }
    }
    __syncthreads();
    if (tid < 128) {
        int r = tid & 63, wr2 = tid >> 6;
        float m1 = red_mx[wr2][0][r], s1 = red_sm[wr2][0][r];
        float m2 = red_mx[wr2][1][r], s2 = red_sm[wr2][1][r];
        float nm = fmaxf(m1, m2);
        float s = s1 * __expf(m1 - nm) + s2 * __expf(m2 - nm);
        int gm = m0 + wr2 * 64 + r;
        pmax[(size_t)gm * NT_PAD + nt] = nm;
        psum[(size_t)gm * NT_PAD + nt] = s;
    }
}

// ---- combine per-tile partials -> lse[m], one wave per row ----
__global__ void lse_wave_k(const float* __restrict__ pmax, const float* __restrict__ psum,
                           float* __restrict__ lse) {
    int gw = (blockIdx.x * blockDim.x + threadIdx.x) >> 6;
    int ln = threadIdx.x & 63;
    if (gw >= MM) return;
    const float* pm = pmax + (size_t)gw * NT_PAD;
    const float* ps = psum + (size_t)gw * NT_PAD;
    float M = -1e30f, S = 0.f;
    for (int t = ln; t < NTILE; t += 64) {
        float m2 = pm[t], s2 = ps[t];
        float nm = fmaxf(M, m2);
        S = S * __expf(M - nm) + s2 * __expf(m2 - nm);
        M = nm;
    }
#pragma unroll
    for (int o = 1; o < 64; o <<= 1) {
        float m2 = __shfl_xor(M, o);
        float s2 = __shfl_xor(S, o);
        float nm = fmaxf(M, m2);
        S = S * __expf(M - nm) + s2 * __expf(m2 - nm);
        M = nm;
    }
    if (ln == 0) lse[gw] = M + __logf(S);
}

// ---- finalize DENSE: no map read — out = log(pg*exp(l-L)+1e-40).
//      Mapped entries corrected afterwards by scatter_fix_k. ----
__global__ void finalize_dense_k(const unsigned short* __restrict__ logb,
                                 float* __restrict__ out, const float* __restrict__ pgen,
                                 const float* __restrict__ lse, const int* __restrict__ tempp) {
    int m = blockIdx.y;
    float invt = get_invtemp(tempp);
    float pg = pgen[m], L = lse[m];
    int sk = (-m) & 3, pad = m & 3;
    int nchunk = (VV - sk) >> 2;
    const unsigned short* lrow = logb + (size_t)m * VPAD + pad;
    size_t base = (size_t)m * VV;
    int c = blockIdx.x * 256 + threadIdx.x;
    if (c < nchunk) {
        int v0 = sk + 4 * c;
        ushort4 lb = *(const ushort4*)(lrow + v0);   // (pad+sk)%4==0 -> aligned
        unsigned short ls[4] = {lb.x, lb.y, lb.z, lb.w};
        float rs[4];
#pragma unroll
        for (int j = 0; j < 4; j++)
            rs[j] = __logf(pg * __expf(bf2f(ls[j]) * invt - L) + 1e-40f);
        float4 o4 = {rs[0], rs[1], rs[2], rs[3]};
        *(float4*)(out + base + sk + 4 * c) = o4;    // aligned 16B
    }
    if (blockIdx.x == 0 && threadIdx.x == 0) {
        for (int v = 0; v < sk; v++)
            out[base + v] = __logf(pg * __expf(bf2f(lrow[v]) * invt - L) + 1e-40f);
        for (int v = sk + 4 * nchunk; v < VV; v++)
            out[base + v] = __logf(pg * __expf(bf2f(lrow[v]) * invt - L) + 1e-40f);
    }
}

// ---- sparse correction: one block per (b,s) slot; rewrites mapped entries.
//      Each (m, canonical id) written exactly once -> deterministic. ----
__global__ void scatter_fix_k(const int* __restrict__ enc, const int* __restrict__ mapv,
                              const unsigned short* __restrict__ logb,
                              float* __restrict__ out, const float* __restrict__ pgen,
                              const float* __restrict__ lse, const float* __restrict__ Aacc,
                              const int* __restrict__ tempp) {
    int t = blockIdx.x;            // 0 .. BB*SS-1
    int b = t / SS, s = t % SS;
    int id = enc[b * SS + s];
    if (mapv[(size_t)b * VV + id] - 1 != s) return;   // not the canonical slot
    float invt = get_invtemp(tempp);
    int tid = threadIdx.x;
    for (int mo = tid; mo < TT; mo += 256) {
        int m = b * TT + mo;
        float l = bf2f(logb[(size_t)m * VPAD + (m & 3) + id]);
        float p = pgen[m] * __expf(l * invt - lse[m]) + Aacc[(size_t)m * SS + s];
        out[(size_t)m * VV + id] = __logf(p + 1e-40f);
    }
}

// ---- finalize in-place from f32 logits (middle/fallback path) ----
__global__ void finalize_k(float* __restrict__ out, const float* __restrict__ pgen,
                           const float* __restrict__ lse, const int* __restrict__ mapv,
                           const float* __restrict__ Aacc, const int* __restrict__ tempp) {
    int m = blockIdx.y;
    int b = m >> 9;
    float invt = get_invtemp(tempp);
    float pg = pgen[m], L = lse[m];
    size_t base = (size_t)m * VV;
    const int* mrow = mapv + (size_t)b * VV;
    const float* arow = Aacc + (size_t)m * SS;
    int sk = (-m) & 3;
    int nchunk = (VV - sk) >> 2;
    int c = blockIdx.x * 256 + threadIdx.x;
    if (c < nchunk) {
        int v0 = sk + 4 * c;
        float4 l4 = *(const float4*)(out + base + v0);
        float xs[4] = {l4.x, l4.y, l4.z, l4.w};
        float rs[4];
#pragma unroll
        for (int j = 0; j < 4; j++) {
            float p = pg * __expf(xs[j] * invt - L);
            int jm = mrow[v0 + j];
            if (jm) p += arow[jm - 1];
            rs[j] = __logf(p + 1e-40f);
        }
        float4 o4 = {rs[0], rs[1], rs[2], rs[3]};
        *(float4*)(out + base + v0) = o4;
    }
    if (blockIdx.x == 0 && threadIdx.x == 0) {
        for (int v = 0; v < sk; v++) {
            float p = pg * __expf(out[base + v] * invt - L);
            int jm = mrow[v];
            if (jm) p += arow[jm - 1];
            out[base + v] = __logf(p + 1e-40f);
        }
        for (int v = sk + 4 * nchunk; v < VV; v++) {
            float p = pg * __expf(out[base + v] * invt - L);
            int jm = mrow[v];
            if (jm) p += arow[jm - 1];
            out[base + v] = __logf(p + 1e-40f);
        }
    }
}

// ---- fallback GEMM (round-1 version, f32 W inline convert) ----
__global__ __launch_bounds__(256) void gemm_old_k(
    const unsigned short* __restrict__ xb, const float* __restrict__ W,
    const float* __restrict__ bias, float* __restrict__ out) {
    __shared__ unsigned short As[128][40];
    __shared__ unsigned short Bs[128][40];
    int bid = blockIdx.x;
    int mt = bid & 7;
    int nt = bid >> 3;
    int m0 = mt * 128, n0 = nt * 128;
    int tid = threadIdx.x;
    int lid = tid & 63, w = tid >> 6;
    int wr = w >> 1, wc = w & 1;
    int row16 = lid & 15, kg = lid >> 4;

    f32x4 acc[4][4];
#pragma unroll
    for (int i = 0; i < 4; i++)
#pragma unroll
        for (int j = 0; j < 4; j++) acc[i][j] = (f32x4){0.f, 0.f, 0.f, 0.f};

    int tr = tid >> 3;
    int tc = (tid & 7) << 2;

    for (int kt = 0; kt < HH / 32; ++kt) {
        int k0 = kt * 32;
        __syncthreads();
#pragma unroll
        for (int i = 0; i < 4; i++) {
            int r = tr + 32 * i;
            ushort4 a4 = *(const ushort4*)&xb[(size_t)(m0 + r) * HH + k0 + tc];
            *(ushort4*)&As[r][tc] = a4;
            int v = n0 + r; v = (v < VV) ? v : (VV - 1);
            float4 w4 = *(const float4*)&W[(size_t)v * HH + k0 + tc];
            ushort4 b4;
            b4.x = f2bf(w4.x); b4.y = f2bf(w4.y); b4.z = f2bf(w4.z); b4.w = f2bf(w4.w);
            *(ushort4*)&Bs[r][tc] = b4;
        }
        __syncthreads();
        short8 af[4], bf[4];
#pragma unroll
        for (int i = 0; i < 4; i++) {
            af[i] = *(const short8*)&As[wr * 64 + i * 16 + row16][kg * 8];
            bf[i] = *(const short8*)&Bs[wc * 64 + i * 16 + row16][kg * 8];
        }
#pragma unroll
        for (int mi = 0; mi < 4; mi++)
#pragma unroll
            for (int ni = 0; ni < 4; ni++)
                acc[mi][ni] = __builtin_amdgcn_mfma_f32_16x16x32_bf16(af[mi], bf[ni], acc[mi][ni], 0, 0, 0);
    }
#pragma unroll
    for (int ni = 0; ni < 4; ni++) {
        int gnv = n0 + wc * 64 + ni * 16 + row16;
        if (gnv < VV) {
            float bvv = bias[gnv];
#pragma unroll
            for (int mi = 0; mi < 4; mi++) {
                int gmb = m0 + wr * 64 + mi * 16 + (kg << 2);
#pragma unroll
                for (int j = 0; j < 4; j++)
                    out[(size_t)(gmb + j) * VV + gnv] = acc[mi][ni][j] + bvv;
            }
        }
    }
}

// ---- per-row lse over V (fallback path only) ----
__global__ void rowreduce_k(const float* __restrict__ out, float* __restrict__ lse,
                            const int* __restrict__ tempp) {
    int m = blockIdx.x, tid = threadIdx.x;
    float invt = get_invtemp(tempp);
    const float* row = out + (size_t)m * VV;
    int sk = (-m) & 3;
    int nchunk = (VV - sk) >> 2;
    float mi = -1e30f, si = 0.f;
    for (int c = tid; c < nchunk; c += 256) {
        float4 x4 = *(const float4*)(row + sk + 4 * c);
        float xs[4] = {x4.x, x4.y, x4.z, x4.w};
#pragma unroll
        for (int j = 0; j < 4; j++) {
            float x = xs[j] * invt;
            float nm = fmaxf(mi, x);
            si = si * __expf(mi - nm) + __expf(x - nm);
            mi = nm;
        }
    }
    if (tid == 0) {
        for (int v = 0; v < sk; v++) {
            float x = row[v] * invt;
            float nm = fmaxf(mi, x);
            si = si * __expf(mi - nm) + __expf(x - nm);
            mi = nm;
        }
        for (int v = sk + 4 * nchunk; v < VV; v++) {
            float x = row[v] * invt;
            float nm = fmaxf(mi, x);
            si = si * __expf(mi - nm) + __expf(x - nm);
            mi = nm;
        }
    }
    __shared__ float sm[256], ss[256];
    sm[tid] = mi; ss[tid] = si; __syncthreads();
    for (int h = 128; h; h >>= 1) {
        if (tid < h) {
            float m2 = sm[tid + h], s2 = ss[tid + h];
            float nm = fmaxf(sm[tid], m2);
            ss[tid] = ss[tid] * __expf(sm[tid] - nm) + s2 * __expf(m2 - nm);
            sm[tid] = nm;
        }
        __syncthreads();
    }
    if (tid == 0) lse[m] = sm[0] + __logf(ss[0]);
}

extern "C" void kernel_launch(void* const* d_in, const int* in_sizes, int n_in,
                              void* d_out, int out_size, void* d_ws, size_t ws_size,
                              hipStream_t stream) {
    const float* x      = (const float*)d_in[0];
    const float* attn   = (const float*)d_in[1];
    const int*   enc    = (const int*)d_in[2];
    const int*   temp   = (const int*)d_in[3];
    const float* proj_w = (const float*)d_in[4];
    const float* proj_b = (const float*)d_in[5];
    const float* pgen_w = (const float*)d_in[6];
    const float* pgen_b = (const float*)d_in[7];
    float* out = (float*)d_out;

    char* ws = (char*)d_ws;
    const size_t WB_BYTES = (size_t)VPAD * HH * 2;       // 103,022,592

    size_t o_wb   = 0;
    size_t o_xb   = o_wb + WB_BYTES;
    size_t o_pgen = o_xb + 2097152;
    size_t o_lse  = o_pgen + 4096;
    size_t o_map  = o_lse + 4096;
    size_t o_aacc = o_map + 402432;
    size_t o_pmax = o_aacc + (size_t)MM * SS * 4;
    size_t o_psum = o_pmax + (size_t)MM * NT_PAD * 4;
    size_t o_logb = o_psum + (size_t)MM * NT_PAD * 4;    // 110,445,568
    size_t need_mid = o_logb;                            // ~110.4 MB
    size_t need_big = o_logb + (size_t)MM * VPAD * 2;    // ~213.5 MB

    if (ws_size >= need_mid) {
        unsigned short* wb   = (unsigned short*)(ws + o_wb);
        unsigned short* xb   = (unsigned short*)(ws + o_xb);
        float*          pgen = (float*)(ws + o_pgen);
        float*          lse  = (float*)(ws + o_lse);
        int*            mapv = (int*)(ws + o_map);
        float*          Aacc = (float*)(ws + o_aacc);
        float*          pmax = (float*)(ws + o_pmax);
        float*          psum = (float*)(ws + o_psum);
        unsigned short* logb = (unsigned short*)(ws + o_logb);

        zero1_k<<<256, 256, 0, stream>>>(mapv, BB * VV);
        cvtx_pgen_k<<<MM, 256, 0, stream>>>(x, pgen_w, pgen_b, xb, pgen);
        cvt_w_k<<<(VPAD * HH / 8 + 255) / 256, 256, 0, stream>>>(proj_w, wb);
        map_build_k<<<4, 256, 0, stream>>>(enc, mapv);
        attn_k<<<MM, 256, 0, stream>>>(attn, enc, mapv, pgen, Aacc, temp);
        if (ws_size >= need_big) {
            gemm10_k<1><<<8 * NT_PAD, 256, 0, stream>>>(xb, wb, proj_b, out, logb, pmax, psum, temp);
            lse_wave_k<<<256, 256, 0, stream>>>(pmax, psum, lse);
            finalize_dense_k<<<dim3(50, MM), 256, 0, stream>>>(logb, out, pgen, lse, temp);
            scatter_fix_k<<<BB * SS, 256, 0, stream>>>(enc, mapv, logb, out, pgen, lse, Aacc, temp);
        } else {
            gemm10_k<0><<<8 * NT_PAD, 256, 0, stream>>>(xb, wb, proj_b, out, logb, pmax, psum, temp);
            lse_wave_k<<<256, 256, 0, stream>>>(pmax, psum, lse);
            finalize_k<<<dim3(50, MM), 256, 0, stream>>>(out, pgen, lse, mapv, Aacc, temp);
        }
    } else {
        unsigned short* xb   = (unsigned short*)(ws + 0);
        float*          pgen = (float*)(ws + 2097152);
        float*          lse  = (float*)(ws + 2101248);
        int*            mapv = (int*)(ws + 2105344);
        float*          Aacc = (float*)(ws + 2507776);

        zero1_k<<<256, 256, 0, stream>>>(mapv, BB * VV);
        cvtx_pgen_k<<<MM, 256, 0, stream>>>(x, pgen_w, pgen_b, xb, pgen);
        map_build_k<<<4, 256, 0, stream>>>(enc, mapv);
        attn_k<<<MM, 256, 0, stream>>>(attn, enc, mapv, pgen, Aacc, temp);
        gemm_old_k<<<8 * NTILE, 256, 0, stream>>>(xb, proj_w, proj_b, out);
        rowreduce_k<<<MM, 256, 0, stream>>>(out, lse, temp);
        finalize_k<<<dim3(50, MM), 256, 0, stream>>>(out, pgen, lse, mapv, Aacc, temp);
    }
}